// Round 1
// baseline (301.578 us; speedup 1.0000x reference)
//
#include <hip/hip_runtime.h>

#define NBINS   256
#define B       64
#define NPB     786432          // 3*512*512 elements per batch
#define NF4     (NPB / 4)       // 196608 float4 per batch
#define BPB     16              // blocks per batch
#define THREADS 256

// Order-preserving float<->uint encoding so atomicMin/atomicMax on unsigned
// give float min/max.
__device__ __forceinline__ unsigned fenc(float f) {
    unsigned u = __float_as_uint(f);
    return (u & 0x80000000u) ? ~u : (u | 0x80000000u);
}
__device__ __forceinline__ float fdec(unsigned u) {
    unsigned v = (u & 0x80000000u) ? (u & 0x7FFFFFFFu) : ~u;
    return __uint_as_float(v);
}

// ws layout: [0..127]   encoded minmax (2 per batch: min, max)
//            [128..128+B*NBINS-1] per-batch histograms (u32)
__global__ __launch_bounds__(THREADS) void k_init(unsigned* __restrict__ mm,
                                                  unsigned* __restrict__ hist) {
    int i = blockIdx.x * blockDim.x + threadIdx.x;
    if (i < B) { mm[2 * i] = 0xFFFFFFFFu; mm[2 * i + 1] = 0u; }
    if (i < B * NBINS) hist[i] = 0u;
}

__global__ __launch_bounds__(THREADS) void k_minmax(const float4* __restrict__ x,
                                                    unsigned* __restrict__ mm) {
    const int batch = blockIdx.x / BPB;
    const int blk   = blockIdx.x % BPB;
    const float4* p = x + (long long)batch * NF4;

    float mn = 3.402823466e38f, mx = -3.402823466e38f;
    int t = blk * THREADS + threadIdx.x;
    // NF4 / (BPB*THREADS) = 48 exact, no tail
    #pragma unroll 4
    for (int i = t; i < NF4; i += BPB * THREADS) {
        float4 v = p[i];
        mn = fminf(mn, fminf(fminf(v.x, v.y), fminf(v.z, v.w)));
        mx = fmaxf(mx, fmaxf(fmaxf(v.x, v.y), fmaxf(v.z, v.w)));
    }
    // wave64 reduce
    for (int o = 32; o > 0; o >>= 1) {
        mn = fminf(mn, __shfl_down(mn, o));
        mx = fmaxf(mx, __shfl_down(mx, o));
    }
    __shared__ float smn[4], smx[4];
    int wid = threadIdx.x >> 6;
    if ((threadIdx.x & 63) == 0) { smn[wid] = mn; smx[wid] = mx; }
    __syncthreads();
    if (threadIdx.x == 0) {
        mn = fminf(fminf(smn[0], smn[1]), fminf(smn[2], smn[3]));
        mx = fmaxf(fmaxf(smx[0], smx[1]), fmaxf(smx[2], smx[3]));
        atomicMin(&mm[2 * batch],     fenc(mn));
        atomicMax(&mm[2 * batch + 1], fenc(mx));
    }
}

__global__ __launch_bounds__(THREADS) void k_hist(const float4* __restrict__ x,
                                                  const unsigned* __restrict__ mm,
                                                  unsigned* __restrict__ hist) {
    const int batch = blockIdx.x / BPB;
    const int blk   = blockIdx.x % BPB;

    // 4 per-wave replicas to cut LDS-atomic contention
    __shared__ unsigned lh[4][NBINS];
    for (int i = threadIdx.x; i < 4 * NBINS; i += THREADS)
        ((unsigned*)lh)[i] = 0u;
    __syncthreads();

    const float mn = fdec(mm[2 * batch]);
    const float mx = fdec(mm[2 * batch + 1]);
    // Match reference exactly: rng/lo selection, f32 divide then multiply,
    // truncating int cast, clip [0, 255].
    const float rng   = (mx > mn) ? (mx - mn) : 2.0f;
    const float lo    = (mx > mn) ? mn : (mn - 1.0f);
    const float scale = (float)NBINS / rng;

    unsigned* h = lh[threadIdx.x >> 6];
    const float4* p = x + (long long)batch * NF4;
    int t = blk * THREADS + threadIdx.x;
    for (int i = t; i < NF4; i += BPB * THREADS) {
        float4 v = p[i];
        int i0 = (int)((v.x - lo) * scale);
        int i1 = (int)((v.y - lo) * scale);
        int i2 = (int)((v.z - lo) * scale);
        int i3 = (int)((v.w - lo) * scale);
        i0 = min(max(i0, 0), NBINS - 1);
        i1 = min(max(i1, 0), NBINS - 1);
        i2 = min(max(i2, 0), NBINS - 1);
        i3 = min(max(i3, 0), NBINS - 1);
        atomicAdd(&h[i0], 1u);
        atomicAdd(&h[i1], 1u);
        atomicAdd(&h[i2], 1u);
        atomicAdd(&h[i3], 1u);
    }
    __syncthreads();

    unsigned* gh = hist + batch * NBINS;
    for (int i = threadIdx.x; i < NBINS; i += THREADS) {
        unsigned s = lh[0][i] + lh[1][i] + lh[2][i] + lh[3][i];
        if (s) atomicAdd(&gh[i], s);
    }
}

__global__ __launch_bounds__(THREADS) void k_entropy(const unsigned* __restrict__ hist,
                                                     float* __restrict__ out) {
    // Every element lands in exactly one bin (clip), so per-batch sum == NPB.
    const float invN = 1.0f / (float)NPB;
    float sum = 0.0f;
    for (int b = 0; b < B; ++b) {
        unsigned c = hist[b * NBINS + threadIdx.x];
        if (c) {
            float pv = (float)c * invN;
            sum += pv * log2f(pv);
        }
    }
    for (int o = 32; o > 0; o >>= 1) sum += __shfl_down(sum, o);
    __shared__ float s[4];
    int wid = threadIdx.x >> 6;
    if ((threadIdx.x & 63) == 0) s[wid] = sum;
    __syncthreads();
    if (threadIdx.x == 0)
        out[0] = -(s[0] + s[1] + s[2] + s[3]) / (float)B;
}

extern "C" void kernel_launch(void* const* d_in, const int* in_sizes, int n_in,
                              void* d_out, int out_size, void* d_ws, size_t ws_size,
                              hipStream_t stream) {
    const float* x = (const float*)d_in[0];
    float* out = (float*)d_out;
    unsigned* mm   = (unsigned*)d_ws;          // 128 u32
    unsigned* hist = mm + 2 * B;               // 64*256 u32

    hipLaunchKernelGGL(k_init, dim3((B * NBINS + THREADS - 1) / THREADS),
                       dim3(THREADS), 0, stream, mm, hist);
    hipLaunchKernelGGL(k_minmax, dim3(B * BPB), dim3(THREADS), 0, stream,
                       (const float4*)x, mm);
    hipLaunchKernelGGL(k_hist, dim3(B * BPB), dim3(THREADS), 0, stream,
                       (const float4*)x, mm, hist);
    hipLaunchKernelGGL(k_entropy, dim3(1), dim3(THREADS), 0, stream, hist, out);
}